// Round 7
// baseline (126.073 us; speedup 1.0000x reference)
//
#include <hip/hip_runtime.h>
#include <hip/hip_bf16.h>

#define D_K 576
#define NSLAB 18         // 576 / 32
#define LBDA_INV 2.0f    // 1/lbda, lbda=0.5
#define HALF_LBDA 0.5f
#define EPS 0.01f
#define DSTRIDE 136      // Ds stride: 128 + 8 bf16 pad

typedef __attribute__((ext_vector_type(8))) short short8;
typedef __attribute__((ext_vector_type(4))) float f32x4;

__device__ inline float bf2f(unsigned short s) {
    return __uint_as_float(((unsigned)s) << 16);
}
// packed f32x2 -> bf16x2 (v_cvt_pk_bf16_f32 on gfx950), low half = x
__device__ inline unsigned pack_bf16(float x, float y) {
    __hip_bfloat162 h = __float22bfloat162_rn(float2{x, y});
    return *reinterpret_cast<unsigned*>(&h);
}

// ---------------- soft-min helpers (lbda = 0.5) ----------------
__device__ inline float softmin3(float a, float b, float c) {
    float mn = fminf(a, fminf(b, c));
    float s = __expf(-LBDA_INV * (a - mn)) + __expf(-LBDA_INV * (b - mn)) +
              __expf(-LBDA_INV * (c - mn));
    return mn - HALF_LBDA * __logf(s);
}
__device__ inline float softmin2(float a, float b) {
    float mn = fminf(a, b);
    float s = __expf(-LBDA_INV * (a - mn)) + __expf(-LBDA_INV * (b - mn));
    return mn - HALF_LBDA * __logf(s);
}

// OTAM DP over an 8x8 dist tile; element (l,s) at d[l*RS + s*CS].
template <int RS, int CS>
__device__ float otam_dp(const float* d) {
    float prev[10], cur[10];
    prev[0] = 0.f;
#pragma unroll
    for (int m = 1; m <= 8; ++m) prev[m] = prev[m - 1] + d[0 * RS + (m - 1) * CS];
    prev[9] = prev[8];  // pad col, d=0
#pragma unroll
    for (int l = 1; l < 8; ++l) {
        cur[0] = 0.f;
        cur[1] = d[l * RS + 0 * CS] + softmin3(prev[0], 0.f, prev[1]);
#pragma unroll
        for (int m = 2; m <= 8; ++m)
            cur[m] = d[l * RS + (m - 1) * CS] + softmin2(prev[m - 1], cur[m - 1]);
        cur[9] = softmin3(prev[8], cur[8], prev[9]);
#pragma unroll
        for (int m = 0; m < 10; ++m) prev[m] = cur[m];
    }
    return prev[9];
}

// =====================================================================================
// Single self-contained kernel: per K-step, convert f32 -> bf16 into LDS (packed cvt),
// accumulate row sum-of-squares in registers (norms), MFMA from LDS, then epilogue + DP.
// LDS chunk layout (per slab): chunk (c_in, r) at ushort offset (c_in*128 + (r ^ swz))*8,
// swz = c_in<<1 (bank swizzle; read side applies the same XOR -> reads stay 2-way free).
// =====================================================================================
__global__ __launch_bounds__(256, 2) void fused_kernel(
        const float* __restrict__ sup, const float* __restrict__ qry,
        float* __restrict__ out) {
    __shared__ unsigned short smem[128 * DSTRIDE];   // 34.8 KB; K-loop uses first 16 KB
    __shared__ float qn_l[128], sn_l[128];
    unsigned short* As = smem;
    unsigned short* Bs = smem + 4096;
    unsigned short* Ds = smem;

    const int t = threadIdx.x;
    // XCD swizzle: 4 sblk-siblings of a qblk share an XCD -> A f32 re-reads hit its L2
    const int b = blockIdx.x;
    const int xcd = b & 7, s2 = b >> 3;
    const int sblk = s2 >> 4;                 // 0..3
    const int qblk = xcd * 16 + (s2 & 15);    // 0..127

    const float* Ag = qry + (size_t)qblk * 128 * D_K;
    const float* Bg = sup + (size_t)sblk * 128 * D_K;

    const int lane = t & 63;
    const int wave = t >> 6;
    const int wm = wave >> 1, wn = wave & 1;
    const int col16 = lane & 15, quad = lane >> 4;

    f32x4 acc[4][4];
#pragma unroll
    for (int i = 0; i < 4; ++i)
#pragma unroll
        for (int j = 0; j < 4; ++j) acc[i][j] = (f32x4){0.f, 0.f, 0.f, 0.f};

    // staging geometry: idx = i*256 + t -> row r = i*32 + (t>>3), col-quad c = t&7
    const int srow = t >> 3, scol = t & 7;
    const int c_in = scol >> 1, half = scol & 1;
    // ushort offset of this thread's half-chunk for row r: ((c_in*128 + (r^(c_in<<1)))*8 + half*4
    const int swz = c_in << 1;
    float sq_a[4] = {0.f, 0.f, 0.f, 0.f}, sq_b[4] = {0.f, 0.f, 0.f, 0.f};

    // fragment offsets (ushorts): chunk (quad, row) with the same XOR swizzle
    int aoff[4], boff[4];
#pragma unroll
    for (int mt = 0; mt < 4; ++mt) {
        int m = wm * 64 + mt * 16 + col16;
        aoff[mt] = (quad * 128 + (m ^ (quad << 1))) * 8;
    }
#pragma unroll
    for (int nt = 0; nt < 4; ++nt) {
        int n = wn * 64 + nt * 16 + col16;
        boff[nt] = (quad * 128 + (n ^ (quad << 1))) * 8;
    }

    for (int j = 0; j < NSLAB; ++j) {
        const int kbase = j * 32 + scol * 4;
        // issue all 8 global loads first (overlap), then convert+stage
        float4 va[4], vb[4];
#pragma unroll
        for (int i = 0; i < 4; ++i) {
            int r = i * 32 + srow;
            va[i] = *(const float4*)(Ag + (size_t)r * D_K + kbase);
            vb[i] = *(const float4*)(Bg + (size_t)r * D_K + kbase);
        }
#pragma unroll
        for (int i = 0; i < 4; ++i) {
            int r = i * 32 + srow;
            int off = (c_in * 128 + (r ^ swz)) * 8 + half * 4;
            sq_a[i] += va[i].x * va[i].x + va[i].y * va[i].y +
                       va[i].z * va[i].z + va[i].w * va[i].w;
            sq_b[i] += vb[i].x * vb[i].x + vb[i].y * vb[i].y +
                       vb[i].z * vb[i].z + vb[i].w * vb[i].w;
            *(uint2*)(As + off) = uint2{pack_bf16(va[i].x, va[i].y),
                                        pack_bf16(va[i].z, va[i].w)};
            *(uint2*)(Bs + off) = uint2{pack_bf16(vb[i].x, vb[i].y),
                                        pack_bf16(vb[i].z, vb[i].w)};
        }
        __syncthreads();

        short8 af[4], bf[4];
#pragma unroll
        for (int mt = 0; mt < 4; ++mt) af[mt] = *(const short8*)(As + aoff[mt]);
#pragma unroll
        for (int nt = 0; nt < 4; ++nt) bf[nt] = *(const short8*)(Bs + boff[nt]);
#pragma unroll
        for (int mt = 0; mt < 4; ++mt)
#pragma unroll
            for (int nt = 0; nt < 4; ++nt)
                acc[mt][nt] = __builtin_amdgcn_mfma_f32_16x16x32_bf16(
                    af[mt], bf[nt], acc[mt][nt], 0, 0, 0);
        __syncthreads();
    }

    // norms: octet-reduce this thread's 4 row-partials (cols scol*4.. summed over all j)
#pragma unroll
    for (int i = 0; i < 4; ++i) {
        sq_a[i] += __shfl_down(sq_a[i], 4);
        sq_a[i] += __shfl_down(sq_a[i], 2);
        sq_a[i] += __shfl_down(sq_a[i], 1);
        sq_b[i] += __shfl_down(sq_b[i], 4);
        sq_b[i] += __shfl_down(sq_b[i], 2);
        sq_b[i] += __shfl_down(sq_b[i], 1);
    }
    if ((t & 7) == 0) {
        int r = t >> 3;
#pragma unroll
        for (int i = 0; i < 4; ++i) {
            qn_l[i * 32 + r] = sqrtf(sq_a[i]);
            sn_l[i * 32 + r] = sqrtf(sq_b[i]);
        }
    }
    __syncthreads();

    // epilogue: dist = 1 - num/(|q||s|+eps) -> Ds (bf16); Ds aliases staging (barriered)
    // C/D layout: col = lane&15, row = quad*4 + reg
#pragma unroll
    for (int mt = 0; mt < 4; ++mt) {
#pragma unroll
        for (int reg = 0; reg < 4; ++reg) {
            int m = wm * 64 + mt * 16 + quad * 4 + reg;
            float qv = qn_l[m];
#pragma unroll
            for (int nt = 0; nt < 4; ++nt) {
                int n = wn * 64 + nt * 16 + col16;
                float sv = sn_l[n];
                float dist = 1.f - acc[mt][nt][reg] / (qv * sv + EPS);
                unsigned p = pack_bf16(dist, 0.f);
                Ds[m * DSTRIDE + n] = (unsigned short)(p & 0xFFFF);
            }
        }
    }
    __syncthreads();

    // DP phase: thread t owns pair (ql, sl)
    const int ql = t >> 4, sl = t & 15;
    float d[64];
#pragma unroll
    for (int l = 0; l < 8; ++l) {
        short8 rowv = *(const short8*)(&Ds[(ql * 8 + l) * DSTRIDE + sl * 8]);
#pragma unroll
        for (int jj = 0; jj < 8; ++jj) d[l * 8 + jj] = bf2f((unsigned short)rowv[jj]);
    }
    float r1 = otam_dp<8, 1>(d);   // dists
    float r2 = otam_dp<1, 8>(d);   // dists^T
    int qg = qblk * 16 + ql, sg = sblk * 16 + sl;
    out[qg * 64 + sg] = -(r1 + r2);
}

extern "C" void kernel_launch(void* const* d_in, const int* in_sizes, int n_in,
                              void* d_out, int out_size, void* d_ws, size_t ws_size,
                              hipStream_t stream) {
    const float* sup = (const float*)d_in[0];   // [64, 8, 576]
    const float* qry = (const float*)d_in[1];   // [2048, 8, 576]
    float* out = (float*)d_out;                 // [2048, 64]
    fused_kernel<<<dim3(512), dim3(256), 0, stream>>>(sup, qry, out);
}